// Round 4
// baseline (186.994 us; speedup 1.0000x reference)
//
#include <hip/hip_runtime.h>
#include <math.h>

// DIAGNOSTIC ROUND: identical kernel to R3, but launched TWICE per call.
// Purpose: the harness's fill/restore traffic dominates dur_us and our
// kernel never shows in the top-5 profile. dur_us(R4) - dur_us(R3) gives
// the kernel's true duration. Second launch is idempotent (same outputs).
//
// inputs: [128, 65536, 3] float32 (AoS: x,y,z per point)
// output: [128, 65536, 2] float32 (-phi*deg, psi*deg)

#define DEG_PER_RAD 57.29577951308232f

typedef float vfloat4 __attribute__((ext_vector_type(4)));

__device__ __forceinline__ void point_math(float x, float y, float z,
                                           float& o0, float& o1) {
    float xc = fminf(fmaxf(x, -1.0f), 1.0f);
    o0 = -90.0f * (xc + 1.0f);
    float n = sqrtf(y * y + z * z);
    float psi = acosf(y / n);
    psi = (z < 0.0f) ? -psi : psi;
    o1 = psi * DEG_PER_RAD;
}

__global__ __launch_bounds__(256) void cil_kernel(const vfloat4* __restrict__ in4,
                                                  vfloat4* __restrict__ out4) {
    __shared__ float lds_in[3072];   // 12 KB: 1024 points * 3
    __shared__ float lds_out[2048];  //  8 KB: 1024 points * 2

    const int b = blockIdx.x;
    const int t = threadIdx.x;

    // ---- coalesced global -> LDS ----
    const vfloat4* src = in4 + (size_t)b * 768;
    vfloat4 v0 = src[t];
    vfloat4 v1 = src[t + 256];
    vfloat4 v2 = src[t + 512];
    vfloat4* li4 = (vfloat4*)lds_in;
    li4[t]       = v0;
    li4[t + 256] = v1;
    li4[t + 512] = v2;
    __syncthreads();

    // ---- per-thread: 4 points = 12 floats in, 8 floats out ----
    float p[12];
#pragma unroll
    for (int k = 0; k < 12; ++k) p[k] = lds_in[12 * t + k];

    float o[8];
#pragma unroll
    for (int q = 0; q < 4; ++q)
        point_math(p[3 * q], p[3 * q + 1], p[3 * q + 2], o[2 * q], o[2 * q + 1]);

#pragma unroll
    for (int k = 0; k < 8; ++k) lds_out[8 * t + k] = o[k];
    __syncthreads();

    // ---- coalesced LDS -> global (nontemporal streaming stores) ----
    vfloat4* dst = out4 + (size_t)b * 512;
    vfloat4 w0 = ((vfloat4*)lds_out)[t];
    vfloat4 w1 = ((vfloat4*)lds_out)[t + 256];
    __builtin_nontemporal_store(w0, &dst[t]);
    __builtin_nontemporal_store(w1, &dst[t + 256]);
}

// Tail for n_points % 1024 != 0 (not hit at 128*65536 but kept for safety).
__global__ void cil_tail_kernel(const float* __restrict__ in,
                                float* __restrict__ out,
                                int start_point, int n_points) {
    int p = start_point + blockIdx.x * blockDim.x + threadIdx.x;
    if (p >= n_points) return;
    float x = in[3 * p + 0];
    float y = in[3 * p + 1];
    float z = in[3 * p + 2];
    float o0, o1;
    point_math(x, y, z, o0, o1);
    out[2 * p + 0] = o0;
    out[2 * p + 1] = o1;
}

extern "C" void kernel_launch(void* const* d_in, const int* in_sizes, int n_in,
                              void* d_out, int out_size, void* d_ws, size_t ws_size,
                              hipStream_t stream) {
    const float* in = (const float*)d_in[0];
    float* out = (float*)d_out;
    const int n_points = in_sizes[0] / 3;          // 8388608
    const int n_full_blocks = n_points / 1024;     // 8192

    // Launch the identical work TWICE (diagnostic: second pass is idempotent).
    for (int rep = 0; rep < 2; ++rep) {
        if (n_full_blocks > 0) {
            cil_kernel<<<n_full_blocks, 256, 0, stream>>>((const vfloat4*)in,
                                                          (vfloat4*)out);
        }
        const int tail_start = n_full_blocks * 1024;
        const int tail = n_points - tail_start;
        if (tail > 0) {
            int block = 256;
            int grid = (tail + block - 1) / block;
            cil_tail_kernel<<<grid, block, 0, stream>>>(in, out, tail_start, n_points);
        }
    }
}

// Round 5
// 161.645 us; speedup vs baseline: 1.1568x; 1.1568x over previous
//
#include <hip/hip_runtime.h>
#include <math.h>

// FINAL (revert of R4 diagnostic double-launch).
//
// inputs: [128, 65536, 3] float32 (AoS: x,y,z per point)
// output: [128, 65536, 2] float32 (-phi*deg, psi*deg)
//
// out0 = -90 * (clamp(x,-1,1)+1)
// out1 = sign(z) * acos(y / sqrt(y*y+z*z)) * (180/pi)
//
// Measured (R3 vs R4 double-launch delta): kernel runs in 25.3 us.
// Ideal: 167.8 MB total traffic / 6.7 TB/s achieved fill BW = 25.0 us.
// => ~99% of achievable HBM bandwidth; memory-bound roofline.
//
// Structure: block = 256 threads, 4 points/thread = 1024 points/block.
// All global accesses are per-instruction contiguous (16 B/lane, unit
// inter-lane stride) via LDS staging:
//   in : 768 float4/block -> 3 contiguous loads per thread -> LDS
//   out: LDS -> 512 float4/block -> 2 contiguous nontemporal stores/thread

#define DEG_PER_RAD 57.29577951308232f

// Native vector type: __builtin_nontemporal_store requires a real vector,
// not HIP's struct-based float4.
typedef float vfloat4 __attribute__((ext_vector_type(4)));

__device__ __forceinline__ void point_math(float x, float y, float z,
                                           float& o0, float& o1) {
    float xc = fminf(fmaxf(x, -1.0f), 1.0f);
    o0 = -90.0f * (xc + 1.0f);
    float n = sqrtf(y * y + z * z);
    float psi = acosf(y / n);
    psi = (z < 0.0f) ? -psi : psi;
    o1 = psi * DEG_PER_RAD;
}

__global__ __launch_bounds__(256) void cil_kernel(const vfloat4* __restrict__ in4,
                                                  vfloat4* __restrict__ out4) {
    __shared__ float lds_in[3072];   // 12 KB: 1024 points * 3
    __shared__ float lds_out[2048];  //  8 KB: 1024 points * 2

    const int b = blockIdx.x;
    const int t = threadIdx.x;

    // ---- coalesced global -> LDS ----
    const vfloat4* src = in4 + (size_t)b * 768;
    vfloat4 v0 = src[t];
    vfloat4 v1 = src[t + 256];
    vfloat4 v2 = src[t + 512];
    vfloat4* li4 = (vfloat4*)lds_in;
    li4[t]       = v0;
    li4[t + 256] = v1;
    li4[t + 512] = v2;
    __syncthreads();

    // ---- per-thread: 4 points = 12 floats in, 8 floats out ----
    float p[12];
#pragma unroll
    for (int k = 0; k < 12; ++k) p[k] = lds_in[12 * t + k];

    float o[8];
#pragma unroll
    for (int q = 0; q < 4; ++q)
        point_math(p[3 * q], p[3 * q + 1], p[3 * q + 2], o[2 * q], o[2 * q + 1]);

#pragma unroll
    for (int k = 0; k < 8; ++k) lds_out[8 * t + k] = o[k];
    __syncthreads();

    // ---- coalesced LDS -> global (nontemporal streaming stores) ----
    vfloat4* dst = out4 + (size_t)b * 512;
    vfloat4 w0 = ((vfloat4*)lds_out)[t];
    vfloat4 w1 = ((vfloat4*)lds_out)[t + 256];
    __builtin_nontemporal_store(w0, &dst[t]);
    __builtin_nontemporal_store(w1, &dst[t + 256]);
}

// Tail for n_points % 1024 != 0 (not hit at 128*65536 but kept for safety).
__global__ void cil_tail_kernel(const float* __restrict__ in,
                                float* __restrict__ out,
                                int start_point, int n_points) {
    int p = start_point + blockIdx.x * blockDim.x + threadIdx.x;
    if (p >= n_points) return;
    float x = in[3 * p + 0];
    float y = in[3 * p + 1];
    float z = in[3 * p + 2];
    float o0, o1;
    point_math(x, y, z, o0, o1);
    out[2 * p + 0] = o0;
    out[2 * p + 1] = o1;
}

extern "C" void kernel_launch(void* const* d_in, const int* in_sizes, int n_in,
                              void* d_out, int out_size, void* d_ws, size_t ws_size,
                              hipStream_t stream) {
    const float* in = (const float*)d_in[0];
    float* out = (float*)d_out;
    const int n_points = in_sizes[0] / 3;          // 8388608
    const int n_full_blocks = n_points / 1024;     // 8192

    if (n_full_blocks > 0) {
        cil_kernel<<<n_full_blocks, 256, 0, stream>>>((const vfloat4*)in,
                                                      (vfloat4*)out);
    }
    const int tail_start = n_full_blocks * 1024;
    const int tail = n_points - tail_start;
    if (tail > 0) {
        int block = 256;
        int grid = (tail + block - 1) / block;
        cil_tail_kernel<<<grid, block, 0, stream>>>(in, out, tail_start, n_points);
    }
}